// Round 1
// baseline (959.358 us; speedup 1.0000x reference)
//
#include <hip/hip_runtime.h>
#include <hip/hip_bf16.h>

#define B_DIM 2048
#define M_DIM 8192
#define D_DIM 2048
#define EPSN 1e-8f
#define ALPHA_C 0.5f
#define SIM_T 0.5f

// ---------------- Kernel 1: inverse norms for query and query_set ----------------
__global__ __launch_bounds__(256) void norms_kernel(const float* __restrict__ q,
                                                    const float* __restrict__ s,
                                                    float* __restrict__ rq,
                                                    float* __restrict__ rs) {
    int row = blockIdx.x;
    const float* src;
    float* dst;
    if (row < B_DIM) { src = q + (size_t)row * D_DIM; dst = rq + row; }
    else             { src = s + (size_t)(row - B_DIM) * D_DIM; dst = rs + (row - B_DIM); }
    float acc = 0.f;
    const float4* src4 = (const float4*)src;
    for (int i = threadIdx.x; i < D_DIM / 4; i += 256) {
        float4 v = src4[i];
        acc += v.x * v.x + v.y * v.y + v.z * v.z + v.w * v.w;
    }
    #pragma unroll
    for (int o = 32; o > 0; o >>= 1) acc += __shfl_down(acc, o, 64);
    __shared__ float red[4];
    int lane = threadIdx.x & 63, wid = threadIdx.x >> 6;
    if (lane == 0) red[wid] = acc;
    __syncthreads();
    if (threadIdx.x == 0) {
        float t = red[0] + red[1] + red[2] + red[3];
        *dst = 1.0f / fmaxf(sqrtf(t), EPSN);
    }
}

// ---------------- Kernel 2: fp32 NT GEMM  sims[b,m] = (q[b].s[m]) * rq[b] * rs[m] ----
#define BM 128
#define BN 128
#define BK 16
#define LDA (BM + 4)   // 132 floats = 528 B, multiple of 16 B -> float4-aligned rows

__global__ __launch_bounds__(256, 2) void gemm_nt(const float* __restrict__ A,
                                                  const float* __restrict__ Bm,
                                                  const float* __restrict__ rq,
                                                  const float* __restrict__ rs,
                                                  float* __restrict__ C) {
    __shared__ float As[BK][LDA];
    __shared__ float Bs[BK][LDA];
    const int tid = threadIdx.x;
    const int tx = tid & 15, ty = tid >> 4;
    const int row0 = blockIdx.y * BM;
    const int col0 = blockIdx.x * BN;

    float acc[8][8];
    #pragma unroll
    for (int i = 0; i < 8; i++)
        #pragma unroll
        for (int j = 0; j < 8; j++) acc[i][j] = 0.f;

    const int rA = tid >> 2;           // 0..63
    const int kq = (tid & 3) * 4;      // 0,4,8,12

    const float* pa0 = A  + (size_t)(row0 + rA)      * D_DIM + kq;
    const float* pa1 = A  + (size_t)(row0 + rA + 64) * D_DIM + kq;
    const float* pb0 = Bm + (size_t)(col0 + rA)      * D_DIM + kq;
    const float* pb1 = Bm + (size_t)(col0 + rA + 64) * D_DIM + kq;

    for (int k0 = 0; k0 < D_DIM; k0 += BK) {
        float4 va0 = *(const float4*)(pa0 + k0);
        float4 va1 = *(const float4*)(pa1 + k0);
        float4 vb0 = *(const float4*)(pb0 + k0);
        float4 vb1 = *(const float4*)(pb1 + k0);
        __syncthreads();   // previous iteration's compute done before overwrite
        As[kq + 0][rA] = va0.x; As[kq + 1][rA] = va0.y; As[kq + 2][rA] = va0.z; As[kq + 3][rA] = va0.w;
        As[kq + 0][rA + 64] = va1.x; As[kq + 1][rA + 64] = va1.y; As[kq + 2][rA + 64] = va1.z; As[kq + 3][rA + 64] = va1.w;
        Bs[kq + 0][rA] = vb0.x; Bs[kq + 1][rA] = vb0.y; Bs[kq + 2][rA] = vb0.z; Bs[kq + 3][rA] = vb0.w;
        Bs[kq + 0][rA + 64] = vb1.x; Bs[kq + 1][rA + 64] = vb1.y; Bs[kq + 2][rA + 64] = vb1.z; Bs[kq + 3][rA + 64] = vb1.w;
        __syncthreads();
        #pragma unroll
        for (int k = 0; k < BK; k++) {
            float4 a0 = *(const float4*)&As[k][ty * 4];
            float4 a1 = *(const float4*)&As[k][ty * 4 + 64];
            float4 b0 = *(const float4*)&Bs[k][tx * 4];
            float4 b1 = *(const float4*)&Bs[k][tx * 4 + 64];
            float a[8] = {a0.x, a0.y, a0.z, a0.w, a1.x, a1.y, a1.z, a1.w};
            float b[8] = {b0.x, b0.y, b0.z, b0.w, b1.x, b1.y, b1.z, b1.w};
            #pragma unroll
            for (int i = 0; i < 8; i++)
                #pragma unroll
                for (int j = 0; j < 8; j++)
                    acc[i][j] = fmaf(a[i], b[j], acc[i][j]);
        }
    }

    // epilogue: scale by rq[row]*rs[col], float4 stores
    float rsv[8];
    #pragma unroll
    for (int j = 0; j < 8; j++) {
        int c = (j < 4) ? (tx * 4 + j) : (64 + tx * 4 + (j - 4));
        rsv[j] = rs[col0 + c];
    }
    #pragma unroll
    for (int i = 0; i < 8; i++) {
        int r = row0 + ((i < 4) ? (ty * 4 + i) : (64 + ty * 4 + (i - 4)));
        float sr = rq[r];
        float4 o0 = make_float4(acc[i][0] * sr * rsv[0], acc[i][1] * sr * rsv[1],
                                acc[i][2] * sr * rsv[2], acc[i][3] * sr * rsv[3]);
        float4 o1 = make_float4(acc[i][4] * sr * rsv[4], acc[i][5] * sr * rsv[5],
                                acc[i][6] * sr * rsv[6], acc[i][7] * sr * rsv[7]);
        *(float4*)(C + (size_t)r * M_DIM + col0 + tx * 4)      = o0;
        *(float4*)(C + (size_t)r * M_DIM + col0 + 64 + tx * 4) = o1;
    }
}

// ---------------- Kernel 3: per-row stats + softmax gather + fallbacks ----------------
#define LISTCAP 512

__global__ __launch_bounds__(256) void stats_gather(const float* __restrict__ sims,
                                                    const float* __restrict__ T,
                                                    float* __restrict__ out) {
    const int b = blockIdx.x;
    const int tid = threadIdx.x;
    __shared__ float row[M_DIM];          // 32 KB
    __shared__ float redf[256];
    __shared__ float redg[256];
    __shared__ int   redi[256];
    __shared__ int   lidx[LISTCAP];
    __shared__ float lw[LISTCAP];
    __shared__ int   lcnt_sh;

    // load the sims row into LDS
    const float4* srow = (const float4*)(sims + (size_t)b * M_DIM);
    float4* row4 = (float4*)row;
    for (int i = tid; i < M_DIM / 4; i += 256) row4[i] = srow[i];
    if (tid == 0) lcnt_sh = 0;
    __syncthreads();

    // ---- phase 1: cnt, masked sum, masked max ----
    float psum = 0.f, pmax = -1e30f;
    int pcnt = 0;
    for (int i = tid; i < M_DIM; i += 256) {
        float s = row[i];
        if (s > SIM_T) { pcnt++; psum += s; pmax = fmaxf(pmax, s); }
    }
    redf[tid] = psum; redg[tid] = pmax; redi[tid] = pcnt;
    __syncthreads();
    for (int st = 128; st > 0; st >>= 1) {
        if (tid < st) {
            redf[tid] += redf[tid + st];
            redg[tid] = fmaxf(redg[tid], redg[tid + st]);
            redi[tid] += redi[tid + st];
        }
        __syncthreads();
    }
    const int cnt = redi[0];
    const float mean = redf[0] / (float)max(cnt, 1);
    const float mx = redg[0];
    __syncthreads();

    // ---- phase 2: masked var + argmin|s - mean| (first-index tie-break) ----
    float pvar = 0.f, pbest = 1e30f;
    int pbi = 0x7fffffff;
    for (int i = tid; i < M_DIM; i += 256) {
        float s = row[i];
        if (s > SIM_T) { float d = s - mean; pvar += d * d; }
        float v = fabsf(s - mean);
        if (v < pbest) { pbest = v; pbi = i; }   // ascending i within thread keeps first
    }
    redf[tid] = pvar; redg[tid] = pbest; redi[tid] = pbi;
    __syncthreads();
    for (int st = 128; st > 0; st >>= 1) {
        if (tid < st) {
            redf[tid] += redf[tid + st];
            float v2 = redg[tid + st]; int i2 = redi[tid + st];
            if (v2 < redg[tid] || (v2 == redg[tid] && i2 < redi[tid])) { redg[tid] = v2; redi[tid] = i2; }
        }
        __syncthreads();
    }
    const float var = redf[0] / (float)max(cnt, 1);
    const float dyn = mean - ALPHA_C * sqrtf(var);
    const int closest = redi[0];
    __syncthreads();

    // ---- phase 3: final mask count, softmax denom, compact survivor list ----
    float pden = 0.f;
    int pf = 0;
    for (int i = tid; i < M_DIM; i += 256) {
        float s = row[i];
        if (s > SIM_T && s > dyn) {
            float e = expf(s - mx);
            pden += e; pf++;
            int pos = atomicAdd(&lcnt_sh, 1);
            if (pos < LISTCAP) { lidx[pos] = i; lw[pos] = e; }
        }
    }
    redf[tid] = pden; redi[tid] = pf;
    __syncthreads();
    for (int st = 128; st > 0; st >>= 1) {
        if (tid < st) { redf[tid] += redf[tid + st]; redi[tid] += redi[tid + st]; }
        __syncthreads();
    }
    const float denom = redf[0];
    const int fcnt = redi[0];
    __syncthreads();

    // ---- phase 4: weighted gather / fallbacks ----
    const float4* T4 = (const float4*)T;
    float4 a0 = make_float4(0.f, 0.f, 0.f, 0.f);
    float4 a1 = make_float4(0.f, 0.f, 0.f, 0.f);
    if (cnt == 0) {
        // zeros (fallback 2)
    } else if (fcnt == 0) {
        // fallback 1: target_set[closest]
        a0 = T4[(size_t)closest * (D_DIM / 4) + tid];
        a1 = T4[(size_t)closest * (D_DIM / 4) + tid + 256];
    } else {
        const float rden = 1.0f / denom;
        if (fcnt <= LISTCAP) {
            for (int k = 0; k < fcnt; k++) {
                int m = lidx[k];
                float w = lw[k] * rden;
                float4 t0 = T4[(size_t)m * (D_DIM / 4) + tid];
                float4 t1 = T4[(size_t)m * (D_DIM / 4) + tid + 256];
                a0.x += w * t0.x; a0.y += w * t0.y; a0.z += w * t0.z; a0.w += w * t0.w;
                a1.x += w * t1.x; a1.y += w * t1.y; a1.z += w * t1.z; a1.w += w * t1.w;
            }
        } else {
            for (int m = 0; m < M_DIM; m++) {
                float s = row[m];
                if (s > SIM_T && s > dyn) {
                    float w = expf(s - mx) * rden;
                    float4 t0 = T4[(size_t)m * (D_DIM / 4) + tid];
                    float4 t1 = T4[(size_t)m * (D_DIM / 4) + tid + 256];
                    a0.x += w * t0.x; a0.y += w * t0.y; a0.z += w * t0.z; a0.w += w * t0.w;
                    a1.x += w * t1.x; a1.y += w * t1.y; a1.z += w * t1.z; a1.w += w * t1.w;
                }
            }
        }
    }
    float4* out4 = (float4*)(out + (size_t)b * D_DIM);
    out4[tid] = a0;
    out4[tid + 256] = a1;
}

extern "C" void kernel_launch(void* const* d_in, const int* in_sizes, int n_in,
                              void* d_out, int out_size, void* d_ws, size_t ws_size,
                              hipStream_t stream) {
    const float* query = (const float*)d_in[0];
    const float* qset  = (const float*)d_in[1];
    const float* tset  = (const float*)d_in[2];
    float* out = (float*)d_out;

    char* ws = (char*)d_ws;
    float* sims = (float*)ws;                                     // B*M fp32 = 64 MB
    float* rq   = (float*)(ws + (size_t)B_DIM * M_DIM * sizeof(float));
    float* rs   = rq + B_DIM;

    hipLaunchKernelGGL(norms_kernel, dim3(B_DIM + M_DIM), dim3(256), 0, stream,
                       query, qset, rq, rs);
    hipLaunchKernelGGL(gemm_nt, dim3(M_DIM / BN, B_DIM / BM), dim3(256), 0, stream,
                       query, qset, rq, rs, sims);
    hipLaunchKernelGGL(stats_gather, dim3(B_DIM), dim3(256), 0, stream,
                       sims, tset, out);
}

// Round 2
// 375.017 us; speedup vs baseline: 2.5582x; 2.5582x over previous
//
#include <hip/hip_runtime.h>
#include <hip/hip_bf16.h>

#define B_DIM 2048
#define M_DIM 8192
#define D_DIM 2048
#define EPSN 1e-8f
#define ALPHA_C 0.5f
#define SIM_T 0.5f

typedef __attribute__((ext_vector_type(8))) short short8;
typedef __attribute__((ext_vector_type(4))) float f32x4;

// ---------------- Kernel 1: split fp32 -> bf16 hi/lo + inverse norms ----------------
__global__ __launch_bounds__(256) void prep_kernel(const float* __restrict__ q,
                                                   const float* __restrict__ s,
                                                   ushort* __restrict__ Ah, ushort* __restrict__ Al,
                                                   ushort* __restrict__ Bh, ushort* __restrict__ Bl,
                                                   float* __restrict__ rq, float* __restrict__ rs) {
    const int row = blockIdx.x;
    const int tid = threadIdx.x;
    const float* src;
    ushort *dh, *dl;
    float* dst;
    if (row < B_DIM) {
        src = q + (size_t)row * D_DIM; dh = Ah + (size_t)row * D_DIM;
        dl = Al + (size_t)row * D_DIM; dst = rq + row;
    } else {
        int r = row - B_DIM;
        src = s + (size_t)r * D_DIM; dh = Bh + (size_t)r * D_DIM;
        dl = Bl + (size_t)r * D_DIM; dst = rs + r;
    }
    float acc = 0.f;
    const float4* src4 = (const float4*)src;
    for (int i = tid; i < D_DIM / 4; i += 256) {
        float4 v = src4[i];
        acc += v.x * v.x + v.y * v.y + v.z * v.z + v.w * v.w;
        float xs[4] = {v.x, v.y, v.z, v.w};
        ushort4 h, l;
        ushort* hp = (ushort*)&h; ushort* lp = (ushort*)&l;
        #pragma unroll
        for (int e = 0; e < 4; e++) {
            __hip_bfloat16 hi = __float2bfloat16(xs[e]);            // RNE
            float res = xs[e] - __bfloat162float(hi);
            __hip_bfloat16 lo = __float2bfloat16(res);
            hp[e] = *(ushort*)&hi; lp[e] = *(ushort*)&lo;
        }
        *(ushort4*)(dh + 4 * i) = h;
        *(ushort4*)(dl + 4 * i) = l;
    }
    #pragma unroll
    for (int o = 32; o > 0; o >>= 1) acc += __shfl_down(acc, o, 64);
    __shared__ float red[4];
    int lane = tid & 63, wid = tid >> 6;
    if (lane == 0) red[wid] = acc;
    __syncthreads();
    if (tid == 0) {
        float t = red[0] + red[1] + red[2] + red[3];
        *dst = 1.0f / fmaxf(sqrtf(t), EPSN);
    }
}

// ---------------- Kernel 2: split-bf16 MFMA NT GEMM ----------------
// sims[b,m] = (Ah[b]+Al[b]) . (Bh[m]+Bl[m]) * rq[b] * rs[m], dropping lo.lo
#define TK 32

#define GLOAD_LDS16(g, l) \
    __builtin_amdgcn_global_load_lds((const __attribute__((address_space(1))) void*)(g), \
                                     (__attribute__((address_space(3))) void*)(l), 16, 0, 0)

__global__ __launch_bounds__(256) void gemm_mfma(const ushort* __restrict__ Ah,
                                                 const ushort* __restrict__ Al,
                                                 const ushort* __restrict__ Bh,
                                                 const ushort* __restrict__ Bl,
                                                 const float* __restrict__ rq,
                                                 const float* __restrict__ rs,
                                                 float* __restrict__ C) {
    __shared__ ushort sAh[128][TK];   // 8 KB each, rows contiguous (64 B) — no padding:
    __shared__ ushort sAl[128][TK];   // global_load_lds dest is base + lane*16
    __shared__ ushort sBh[128][TK];
    __shared__ ushort sBl[128][TK];

    const int tid = threadIdx.x;
    const int wave = tid >> 6;
    const int lane = tid & 63;
    const int row0 = blockIdx.y * 128;
    const int col0 = blockIdx.x * 128;
    const int wm = (wave >> 1) * 64;   // wave sub-tile origin in tile
    const int wn = (wave & 1) * 64;

    f32x4 acc[4][4];
    #pragma unroll
    for (int i = 0; i < 4; i++)
        #pragma unroll
        for (int j = 0; j < 4; j++) acc[i][j] = (f32x4){0.f, 0.f, 0.f, 0.f};

    // staging: each wave loads rows [wave*32, wave*32+32) of each of the 4 tiles,
    // as 2 wave-loads x 16 rows (64 lanes * 16 B = 16 rows * 64 B, contiguous).
    const int lrow = lane >> 2;          // 0..15
    const int lke  = (lane & 3) * 8;     // element offset within row
    const size_t gA0 = (size_t)(row0 + wave * 32 + lrow) * D_DIM + lke;
    const size_t gA1 = gA0 + (size_t)16 * D_DIM;
    const size_t gB0 = (size_t)(col0 + wave * 32 + lrow) * D_DIM + lke;
    const size_t gB1 = gB0 + (size_t)16 * D_DIM;
    ushort* lA0 = &sAh[wave * 32][0];      ushort* lA1 = &sAh[wave * 32 + 16][0];
    ushort* lAl0 = &sAl[wave * 32][0];     ushort* lAl1 = &sAl[wave * 32 + 16][0];
    ushort* lB0 = &sBh[wave * 32][0];      ushort* lB1 = &sBh[wave * 32 + 16][0];
    ushort* lBl0 = &sBl[wave * 32][0];     ushort* lBl1 = &sBl[wave * 32 + 16][0];

    const int fr = lane & 15;            // fragment row (m or n)
    const int fq = (lane >> 4) * 8;      // fragment k offset

    for (int k0 = 0; k0 < D_DIM; k0 += TK) {
        __syncthreads();   // previous iter's ds_reads complete before overwrite
        GLOAD_LDS16(Ah + gA0 + k0, lA0);
        GLOAD_LDS16(Ah + gA1 + k0, lA1);
        GLOAD_LDS16(Al + gA0 + k0, lAl0);
        GLOAD_LDS16(Al + gA1 + k0, lAl1);
        GLOAD_LDS16(Bh + gB0 + k0, lB0);
        GLOAD_LDS16(Bh + gB1 + k0, lB1);
        GLOAD_LDS16(Bl + gB0 + k0, lBl0);
        GLOAD_LDS16(Bl + gB1 + k0, lBl1);
        __syncthreads();   // vmcnt(0) drain: tiles resident

        short8 avh[4], avl[4], bvh[4], bvl[4];
        #pragma unroll
        for (int i = 0; i < 4; i++) {
            avh[i] = *(const short8*)&sAh[wm + i * 16 + fr][fq];
            avl[i] = *(const short8*)&sAl[wm + i * 16 + fr][fq];
            bvh[i] = *(const short8*)&sBh[wn + i * 16 + fr][fq];
            bvl[i] = *(const short8*)&sBl[wn + i * 16 + fr][fq];
        }
        #pragma unroll
        for (int i = 0; i < 4; i++)
            #pragma unroll
            for (int j = 0; j < 4; j++) {
                acc[i][j] = __builtin_amdgcn_mfma_f32_16x16x32_bf16(avh[i], bvh[j], acc[i][j], 0, 0, 0);
                acc[i][j] = __builtin_amdgcn_mfma_f32_16x16x32_bf16(avh[i], bvl[j], acc[i][j], 0, 0, 0);
                acc[i][j] = __builtin_amdgcn_mfma_f32_16x16x32_bf16(avl[i], bvh[j], acc[i][j], 0, 0, 0);
            }
    }

    // epilogue: C/D layout col=lane&15, row=(lane>>4)*4+reg
    const int cn = lane & 15;
    const int cr = (lane >> 4) * 4;
    #pragma unroll
    for (int j = 0; j < 4; j++) {
        const int col = col0 + wn + j * 16 + cn;
        const float rsc = rs[col];
        #pragma unroll
        for (int i = 0; i < 4; i++) {
            #pragma unroll
            for (int r = 0; r < 4; r++) {
                const int row = row0 + wm + i * 16 + cr + r;
                C[(size_t)row * M_DIM + col] = acc[i][j][r] * rq[row] * rsc;
            }
        }
    }
}

// ---------------- Kernel 3: per-row stats + softmax gather + fallbacks ----------------
#define LISTCAP 512

__global__ __launch_bounds__(256) void stats_gather(const float* __restrict__ sims,
                                                    const float* __restrict__ T,
                                                    float* __restrict__ out) {
    const int b = blockIdx.x;
    const int tid = threadIdx.x;
    __shared__ float row[M_DIM];          // 32 KB
    __shared__ float redf[256];
    __shared__ float redg[256];
    __shared__ int   redi[256];
    __shared__ int   lidx[LISTCAP];
    __shared__ float lw[LISTCAP];
    __shared__ int   lcnt_sh;

    const float4* srow = (const float4*)(sims + (size_t)b * M_DIM);
    float4* row4 = (float4*)row;
    for (int i = tid; i < M_DIM / 4; i += 256) row4[i] = srow[i];
    if (tid == 0) lcnt_sh = 0;
    __syncthreads();

    // ---- phase 1: cnt, masked sum, masked max ----
    float psum = 0.f, pmax = -1e30f;
    int pcnt = 0;
    for (int i = tid; i < M_DIM; i += 256) {
        float s = row[i];
        if (s > SIM_T) { pcnt++; psum += s; pmax = fmaxf(pmax, s); }
    }
    redf[tid] = psum; redg[tid] = pmax; redi[tid] = pcnt;
    __syncthreads();
    for (int st = 128; st > 0; st >>= 1) {
        if (tid < st) {
            redf[tid] += redf[tid + st];
            redg[tid] = fmaxf(redg[tid], redg[tid + st]);
            redi[tid] += redi[tid + st];
        }
        __syncthreads();
    }
    const int cnt = redi[0];
    const float mean = redf[0] / (float)max(cnt, 1);
    const float mx = redg[0];
    __syncthreads();

    // ---- phase 2: masked var + argmin|s - mean| (first-index tie-break) ----
    float pvar = 0.f, pbest = 1e30f;
    int pbi = 0x7fffffff;
    for (int i = tid; i < M_DIM; i += 256) {
        float s = row[i];
        if (s > SIM_T) { float d = s - mean; pvar += d * d; }
        float v = fabsf(s - mean);
        if (v < pbest) { pbest = v; pbi = i; }
    }
    redf[tid] = pvar; redg[tid] = pbest; redi[tid] = pbi;
    __syncthreads();
    for (int st = 128; st > 0; st >>= 1) {
        if (tid < st) {
            redf[tid] += redf[tid + st];
            float v2 = redg[tid + st]; int i2 = redi[tid + st];
            if (v2 < redg[tid] || (v2 == redg[tid] && i2 < redi[tid])) { redg[tid] = v2; redi[tid] = i2; }
        }
        __syncthreads();
    }
    const float var = redf[0] / (float)max(cnt, 1);
    const float dyn = mean - ALPHA_C * sqrtf(var);
    const int closest = redi[0];
    __syncthreads();

    // ---- phase 3: final mask count, softmax denom, compact survivor list ----
    float pden = 0.f;
    int pf = 0;
    for (int i = tid; i < M_DIM; i += 256) {
        float s = row[i];
        if (s > SIM_T && s > dyn) {
            float e = expf(s - mx);
            pden += e; pf++;
            int pos = atomicAdd(&lcnt_sh, 1);
            if (pos < LISTCAP) { lidx[pos] = i; lw[pos] = e; }
        }
    }
    redf[tid] = pden; redi[tid] = pf;
    __syncthreads();
    for (int st = 128; st > 0; st >>= 1) {
        if (tid < st) { redf[tid] += redf[tid + st]; redi[tid] += redi[tid + st]; }
        __syncthreads();
    }
    const float denom = redf[0];
    const int fcnt = redi[0];
    __syncthreads();

    // ---- phase 4: weighted gather / fallbacks ----
    const float4* T4 = (const float4*)T;
    float4 a0 = make_float4(0.f, 0.f, 0.f, 0.f);
    float4 a1 = make_float4(0.f, 0.f, 0.f, 0.f);
    if (cnt == 0) {
    } else if (fcnt == 0) {
        a0 = T4[(size_t)closest * (D_DIM / 4) + tid];
        a1 = T4[(size_t)closest * (D_DIM / 4) + tid + 256];
    } else {
        const float rden = 1.0f / denom;
        if (fcnt <= LISTCAP) {
            for (int k = 0; k < fcnt; k++) {
                int m = lidx[k];
                float w = lw[k] * rden;
                float4 t0 = T4[(size_t)m * (D_DIM / 4) + tid];
                float4 t1 = T4[(size_t)m * (D_DIM / 4) + tid + 256];
                a0.x += w * t0.x; a0.y += w * t0.y; a0.z += w * t0.z; a0.w += w * t0.w;
                a1.x += w * t1.x; a1.y += w * t1.y; a1.z += w * t1.z; a1.w += w * t1.w;
            }
        } else {
            for (int m = 0; m < M_DIM; m++) {
                float s = row[m];
                if (s > SIM_T && s > dyn) {
                    float w = expf(s - mx) * rden;
                    float4 t0 = T4[(size_t)m * (D_DIM / 4) + tid];
                    float4 t1 = T4[(size_t)m * (D_DIM / 4) + tid + 256];
                    a0.x += w * t0.x; a0.y += w * t0.y; a0.z += w * t0.z; a0.w += w * t0.w;
                    a1.x += w * t1.x; a1.y += w * t1.y; a1.z += w * t1.z; a1.w += w * t1.w;
                }
            }
        }
    }
    float4* out4 = (float4*)(out + (size_t)b * D_DIM);
    out4[tid] = a0;
    out4[tid + 256] = a1;
}

extern "C" void kernel_launch(void* const* d_in, const int* in_sizes, int n_in,
                              void* d_out, int out_size, void* d_ws, size_t ws_size,
                              hipStream_t stream) {
    const float* query = (const float*)d_in[0];
    const float* qset  = (const float*)d_in[1];
    const float* tset  = (const float*)d_in[2];
    float* out = (float*)d_out;

    char* ws = (char*)d_ws;
    size_t off = 0;
    float* sims = (float*)(ws + off); off += (size_t)B_DIM * M_DIM * sizeof(float);   // 64 MB
    ushort* Ah = (ushort*)(ws + off); off += (size_t)B_DIM * D_DIM * sizeof(ushort);  // 8 MB
    ushort* Al = (ushort*)(ws + off); off += (size_t)B_DIM * D_DIM * sizeof(ushort);  // 8 MB
    ushort* Bh = (ushort*)(ws + off); off += (size_t)M_DIM * D_DIM * sizeof(ushort);  // 32 MB
    ushort* Bl = (ushort*)(ws + off); off += (size_t)M_DIM * D_DIM * sizeof(ushort);  // 32 MB
    float* rq  = (float*)(ws + off);  off += B_DIM * sizeof(float);
    float* rs  = (float*)(ws + off);  off += M_DIM * sizeof(float);

    hipLaunchKernelGGL(prep_kernel, dim3(B_DIM + M_DIM), dim3(256), 0, stream,
                       query, qset, Ah, Al, Bh, Bl, rq, rs);
    hipLaunchKernelGGL(gemm_mfma, dim3(M_DIM / 128, B_DIM / 128), dim3(256), 0, stream,
                       Ah, Al, Bh, Bl, rq, rs, sims);
    hipLaunchKernelGGL(stats_gather, dim3(B_DIM), dim3(256), 0, stream,
                       sims, tset, out);
}